// Round 9
// baseline (330.888 us; speedup 1.0000x reference)
//
#include <hip/hip_runtime.h>

typedef unsigned short ushort_t;
typedef unsigned char uchar;
typedef unsigned int uint32;
typedef __attribute__((ext_vector_type(8))) short short8;
typedef __attribute__((ext_vector_type(4))) float f32x4;
typedef __attribute__((ext_vector_type(16))) float f32x16;
typedef __attribute__((ext_vector_type(2))) unsigned int u32x2;
typedef __attribute__((ext_vector_type(2))) long long i64x2;

#define BATCH 8
#define NPTS 12544
#define CC 192
#define KCL 784
#define N2 3136
#define TOTPTS 25088        // BATCH*N2
#define OUT_FEAT_OFF 50176
#define OUT_MASK_OFF 9683968
#define FNEG 3.402823466e38f

__device__ __forceinline__ ushort_t f2bf(float f) {
    union { float f; uint32 u; } v; v.f = f;
    uint32 u = v.u;
    uint32 r = (u + 0x7FFFu + ((u >> 16) & 1u)) >> 16;
    return (ushort_t)r;
}
__device__ __forceinline__ float bf2f(ushort_t h) {
    union { uint32 u; float f; } v; v.u = ((uint32)h) << 16;
    return v.f;
}
__device__ __forceinline__ float gelu_exact(float x) {
    return 0.5f * x * (1.f + erff(x * 0.70710678118654752f));
}
__device__ __forceinline__ uchar f2e4m3(float f) {
    return (uchar)(__builtin_amdgcn_cvt_pk_fp8_f32(f, f, 0, false) & 0xFF);
}
__device__ __forceinline__ int swzc(int c) { return c ^ ((c >> 3) & 7); }

__device__ __forceinline__ void gld16(const void* g, void* l) {
    __builtin_amdgcn_global_load_lds((const __attribute__((address_space(1))) void*)g,
                                     (__attribute__((address_space(3))) void*)l, 16, 0, 0);
}

// JAX threefry2x32 with key = (0, 42)
__device__ __forceinline__ void threefry(uint32 x0, uint32 x1, uint32& y0, uint32& y1) {
    const uint32 k0 = 0u, k1 = 42u;
    const uint32 k2 = 0u ^ 42u ^ 0x1BD11BDAu;
#define ROT(v,r) (((v) << (r)) | ((v) >> (32 - (r))))
#define RND(r) { x0 += x1; x1 = ROT(x1, r); x1 ^= x0; }
    x0 += k0; x1 += k1;
    RND(13) RND(15) RND(26) RND(6)
    x0 += k1; x1 += k2 + 1u;
    RND(17) RND(29) RND(16) RND(24)
    x0 += k2; x1 += k0 + 2u;
    RND(13) RND(15) RND(26) RND(6)
    x0 += k0; x1 += k1 + 3u;
    RND(17) RND(29) RND(16) RND(24)
    x0 += k1; x1 += k2 + 4u;
    RND(13) RND(15) RND(26) RND(6)
    x0 += k2; x1 += k0 + 5u;
    y0 = x0; y1 = x1;
#undef RND
#undef ROT
}

// ---------------- LayerNorm of feat -> bf16 ----------------
__global__ __launch_bounds__(256) void k_ln(const float* __restrict__ x,
        const float* __restrict__ g, const float* __restrict__ b,
        ushort_t* __restrict__ y)
{
    int row = blockIdx.x * 4 + (threadIdx.x >> 6);
    int lane = threadIdx.x & 63;
    const float* xr = x + (size_t)row * CC;
    float v0 = xr[lane], v1 = xr[lane + 64], v2 = xr[lane + 128];
    float s = v0 + v1 + v2;
    for (int d = 32; d >= 1; d >>= 1) s += __shfl_xor(s, d, 64);
    float mu = s * (1.f / 192.f);
    float d0 = v0 - mu, d1 = v1 - mu, d2 = v2 - mu;
    float q = d0 * d0 + d1 * d1 + d2 * d2;
    for (int d = 32; d >= 1; d >>= 1) q += __shfl_xor(q, d, 64);
    float rstd = 1.f / sqrtf(q * (1.f / 192.f) + 1e-5f);
    ushort_t* yr = y + (size_t)row * CC;
    yr[lane]       = f2bf(d0 * rstd * g[lane]       + b[lane]);
    yr[lane + 64]  = f2bf(d1 * rstd * g[lane + 64]  + b[lane + 64]);
    yr[lane + 128] = f2bf(d2 * rstd * g[lane + 128] + b[lane + 128]);
}

// ---------------- points2img scatter + 2x downsample ----------------
__global__ void k_scatter(const float* __restrict__ pos, int* __restrict__ img)
{
    int t = blockIdx.x * 256 + threadIdx.x;
    int b = t / NPTS, n = t - b * NPTS;
    int x = (int)pos[(size_t)t * 2];
    int y = (int)pos[(size_t)t * 2 + 1];
    img[(size_t)b * NPTS + y * 112 + x] = n;
}

__global__ void k_down(const int* __restrict__ img, int* __restrict__ idxa)
{
    int q = blockIdx.x * 256 + threadIdx.x;
    int b = q / N2, p2 = q - b * N2;
    int r = p2 / 56, c = p2 - r * 56;
    idxa[q] = img[(size_t)b * NPTS + (2 * r) * 112 + 2 * c];
}

// ---------------- lin_W -> fp8 linT[384][6144], K physically permuted ----------------
// physical pos q (within row): block = q>>6, w = q&63; u=(w>>4)&3, v=(w>>3)&1, j=w&7
// logical kappa = 64*(q>>6) + 8u + 32v + j;  c = kappa>>5, k = kappa&31;  K_log = k*192 + c
__global__ __launch_bounds__(256) void k_linT(const float* __restrict__ W, uchar* __restrict__ T)
{
    __shared__ float tile[64][65];
    int q0 = blockIdx.x * 64, n0 = blockIdx.y * 64;
    for (int s = 0; s < 16; ++s) {
        int id = threadIdx.x + s * 256;
        int i = id >> 6, j = id & 63;
        int q = q0 + i;
        int w = q & 63;
        int kap = (q & ~63) + 8 * ((w >> 4) & 3) + 32 * ((w >> 3) & 1) + (w & 7);
        int c = kap >> 5, k = kap & 31;
        tile[i][j] = W[(size_t)(k * 192 + c) * 384 + n0 + j];
    }
    __syncthreads();
    for (int s = 0; s < 16; ++s) {
        int id = threadIdx.x + s * 256;
        int jj = id >> 6, ii = id & 63;
        T[(size_t)(n0 + jj) * 6144 + q0 + ii] = f2e4m3(tile[ii][jj]);
    }
}

// ---------------- precompute f1W MFMA B-fragments (bf16): frag[ks][w][lane][j] ----------------
__global__ __launch_bounds__(256) void k_prep(const float* __restrict__ f1W, ushort_t* __restrict__ frag)
{
    int t = blockIdx.x * 256 + threadIdx.x;   // 12288 total
    int j = t & 7;
    int lane = (t >> 3) & 63;
    int w = (t >> 9) & 3;
    int ks = t >> 11;
    int k = ks * 32 + (lane >> 4) * 8 + j;
    int o = w * 16 + (lane & 15);
    frag[t] = f2bf(f1W[k * 64 + o]);
}

// ---------------- per-point: sampling + weights + agg build (fp8, K-permuted) ----------------
__global__ __launch_bounds__(256) void k_point(
    const float* __restrict__ pos, const float* __restrict__ maskp,
    const int* __restrict__ massign, const int* __restrict__ memidx,
    const float* __restrict__ cmaskp, const ushort_t* __restrict__ featn,
    const int* __restrict__ idxarr, const ushort_t* __restrict__ f1frag,
    const float* __restrict__ w1W, const float* __restrict__ w1b,
    const float* __restrict__ lng, const float* __restrict__ lnb,
    const float* __restrict__ f1b,
    const float* __restrict__ f2W, const float* __restrict__ f2b,
    uchar* __restrict__ agg, float* __restrict__ outbuf, int p0)
{
    __shared__ float scf[128];
    __shared__ float prs[128];
    __shared__ float us[128];
    __shared__ int memv[128];
    __shared__ __align__(16) float fgT[192][4];       // [swzc(c)][m]
    __shared__ __align__(16) ushort_t frelb[4][200];
    __shared__ float prel[4][2];
    __shared__ __align__(16) float wsm[4][32];
    __shared__ float gpart[4][4];
    __shared__ float fwv[4];

    int point = p0 + blockIdx.x;
    int b = point / N2;
    int tid = threadIdx.x;
    int wave = tid >> 6, lane = tid & 63;
    int l15 = lane & 15, l4 = lane >> 4;
    int idx_pt = idxarr[point];
    size_t browbase = (size_t)b * NPTS;

    // phase 1: scoring (128 threads)
    if (tid < 128) {
        int j = tid >> 4, i = tid & 15;
        int maj = massign[(browbase + idx_pt) * 8 + j];
        size_t roff = ((size_t)b * KCL + maj) * 16 + i;
        int mv = memidx[roff];
        float cv = cmaskp[roff];
        if (mv == idx_pt) cv = 0.f;
        float pr = fmaxf(cv, 1e-5f);
        uint32 gi = (uint32)point * 128u + (uint32)tid;
        uint32 y0, y1;
        threefry(0u, gi, y0, y1);
        uint32 bits = y0 ^ y1;
        union { uint32 u; float f; } cu; cu.u = (bits >> 9) | 0x3f800000u;
        float u = cu.f - 1.0f;
        float gum = -logf(-logf(u + 1e-20f) + 1e-20f);
        scf[tid] = logf(pr) + gum;
        prs[tid] = pr;
        us[tid] = u;
        memv[tid] = mv;
    }
    __syncthreads();   // #1

    float pdx = pos[(browbase + idx_pt) * 2];
    float pdy = pos[(browbase + idx_pt) * 2 + 1];
    if (wave == 3 && lane == 0) {
        outbuf[OUT_MASK_OFF + point] = maskp[browbase + idx_pt];
        outbuf[(size_t)point * 2]     = floorf(pdx * 0.5f);
        outbuf[(size_t)point * 2 + 1] = floorf(pdy * 0.5f);
    }

    // phase 2: per-wave redundant top-4 (barrierless)
    float a0 = scf[lane], a1 = scf[lane + 64];
    float tops[4]; int topi[4];
#pragma unroll
    for (int pass = 0; pass < 4; ++pass) {
        float s; int si;
        if (a0 >= a1) { s = a0; si = lane; } else { s = a1; si = lane + 64; }
#pragma unroll
        for (int d = 32; d >= 1; d >>= 1) {
            float s2 = __shfl_xor(s, d, 64);
            int i2 = __shfl_xor(si, d, 64);
            if (s2 > s || (s2 == s && i2 < si)) { s = s2; si = i2; }
        }
        tops[pass] = s; topi[pass] = si;
        if (si == lane) a0 = -FNEG;
        if (si == lane + 64) a1 = -FNEG;
    }
    int mc0 = memv[topi[0]], mc1 = memv[topi[1]], mc2 = memv[topi[2]];
    if (tops[2] - tops[3] < 1e-4f) {
        double b0 = log((double)prs[lane]) - log(-log((double)us[lane] + 1e-20) + 1e-20);
        double b1 = log((double)prs[lane + 64]) - log(-log((double)us[lane + 64] + 1e-20) + 1e-20);
        int mcs[3];
#pragma unroll
        for (int pass = 0; pass < 3; ++pass) {
            double s; int si;
            if (b0 >= b1) { s = b0; si = lane; } else { s = b1; si = lane + 64; }
            for (int d = 32; d >= 1; d >>= 1) {
                double s2 = __shfl_xor(s, d, 64);
                int i2 = __shfl_xor(si, d, 64);
                if (s2 > s || (s2 == s && i2 < si)) { s = s2; si = i2; }
            }
            mcs[pass] = memv[si];
            if (si == lane) b0 = -1.0e300;
            if (si == lane + 64) b1 = -1.0e300;
        }
        mc0 = mcs[0]; mc1 = mcs[1]; mc2 = mcs[2];
    }
    int myrow = idx_pt;
    if (wave == 0) myrow = mc0;
    else if (wave == 1) myrow = mc1;
    else if (wave == 2) myrow = mc2;

    // phase 3: gather (wave m -> row myrow) into swizzled c-major fgT
    {
        size_t rbase = (browbase + myrow) * (size_t)CC;
#pragma unroll
        for (int jj = 0; jj < 3; ++jj) {
            int c = lane + jj * 64;
            fgT[swzc(c)][wave] = bf2f(featn[rbase + c]);
        }
        if (lane == 0) {
            prel[wave][0] = pos[(browbase + myrow) * 2]     - pdx;
            prel[wave][1] = pos[(browbase + myrow) * 2 + 1] - pdy;
        }
    }
    __syncthreads();   // #2

    // phase 4a: frelb build (768 elems / 256 threads) from fgT
#pragma unroll
    for (int it = 0; it < 3; ++it) {
        int idx = it * 256 + tid;
        int mm = idx / 192, cq = idx - mm * 192;
        int sc_ = swzc(cq);
        frelb[mm][cq] = f2bf(fgT[sc_][mm] - fgT[sc_][3]);
    }
    // phase 4b: pos MLP (128 threads)
    if (tid < 128) {
        int mm = tid >> 5, kk = tid & 31;
        float pre = prel[mm][0] * w1W[kk] + prel[mm][1] * w1W[32 + kk] + w1b[kk];
        float s = pre;
        for (int d = 16; d >= 1; d >>= 1) s += __shfl_xor(s, d, 32);
        float mu = s * (1.f / 32.f);
        float dv = pre - mu;
        float vs = dv * dv;
        for (int d = 16; d >= 1; d >>= 1) vs += __shfl_xor(vs, d, 32);
        float var = vs * (1.f / 32.f);
        float nv = dv / sqrtf(var + 1e-5f) * lng[kk] + lnb[kk];
        wsm[mm][kk] = gelu_exact(nv);
    }
    __syncthreads();   // #3

    // phase 5: gate MFMA; wave w owns o-tile w*16
    {
        f32x4 acc = (f32x4){0.f, 0.f, 0.f, 0.f};
#pragma unroll
        for (int ks = 0; ks < 6; ++ks) {
            short8 av;
            if (l15 < 4) av = *(const short8*)(&frelb[l15][ks * 32 + l4 * 8]);
            else av = (short8){0,0,0,0,0,0,0,0};
            short8 bv = *(const short8*)(f1frag + ((size_t)(ks * 4 + wave) * 64 + lane) * 8);
            acc = __builtin_amdgcn_mfma_f32_16x16x32_bf16(av, bv, acc, 0, 0, 0);
        }
        float p0_ = 0.f, p1_ = 0.f, p2_ = 0.f, p3_ = 0.f;
        if (l4 == 0) {
            int o = wave * 16 + l15;
            float fb = f1b[o], fw2 = f2W[o];
            p0_ = gelu_exact(acc[0] + fb) * fw2;
            p1_ = gelu_exact(acc[1] + fb) * fw2;
            p2_ = gelu_exact(acc[2] + fb) * fw2;
            p3_ = gelu_exact(acc[3] + fb) * fw2;
        }
        for (int d = 8; d >= 1; d >>= 1) {
            p0_ += __shfl_xor(p0_, d, 64);
            p1_ += __shfl_xor(p1_, d, 64);
            p2_ += __shfl_xor(p2_, d, 64);
            p3_ += __shfl_xor(p3_, d, 64);
        }
        if (lane == 0) { gpart[wave][0] = p0_; gpart[wave][1] = p1_; gpart[wave][2] = p2_; gpart[wave][3] = p3_; }
    }
    __syncthreads();   // #4
    if (tid < 4) {
        float t = gpart[0][tid] + gpart[1][tid] + gpart[2][tid] + gpart[3][tid] + f2b[0];
        fwv[tid] = 1.f / (1.f + expf(-t));
    }
    __syncthreads();   // #5

    // phase 6: agg[kappa = c*32+k] = sum_m (wsm[m][k]*fwv[m]) * fg[m][c] -> fp8, K-permuted layout
    {
        int r = tid & 3, q = tid >> 2;     // k0 = 8r, c0 = 3q
        float fv0 = fwv[0], fv1 = fwv[1], fv2 = fwv[2], fv3 = fwv[3];
        float wv[4][8];
#pragma unroll
        for (int m = 0; m < 4; ++m) {
            f32x4 lo = *(const f32x4*)(&wsm[m][8 * r]);
            f32x4 hi = *(const f32x4*)(&wsm[m][8 * r + 4]);
            wv[m][0] = lo[0]; wv[m][1] = lo[1]; wv[m][2] = lo[2]; wv[m][3] = lo[3];
            wv[m][4] = hi[0]; wv[m][5] = hi[1]; wv[m][6] = hi[2]; wv[m][7] = hi[3];
        }
        uchar* prow = agg + (size_t)point * 6144;
#pragma unroll
        for (int i3 = 0; i3 < 3; ++i3) {
            int c = 3 * q + i3;
            f32x4 g = *(const f32x4*)(&fgT[swzc(c)][0]);
            float g0 = g[0] * fv0, g1 = g[1] * fv1, g2 = g[2] * fv2, g3 = g[3] * fv3;
            float v[8];
#pragma unroll
            for (int i = 0; i < 8; ++i)
                v[i] = g0 * wv[0][i] + g1 * wv[1][i] + g2 * wv[2][i] + g3 * wv[3][i];
            uint32 w0_ = __builtin_amdgcn_cvt_pk_fp8_f32(v[0], v[1], 0, false);
            w0_ = __builtin_amdgcn_cvt_pk_fp8_f32(v[2], v[3], w0_, true);
            uint32 w1_ = __builtin_amdgcn_cvt_pk_fp8_f32(v[4], v[5], 0, false);
            w1_ = __builtin_amdgcn_cvt_pk_fp8_f32(v[6], v[7], w1_, true);
            // physical: 64*(c>>1) + 16*r + 8*(c&1)
            *(u32x2*)(prow + 64 * (c >> 1) + 16 * r + 8 * (c & 1)) = (u32x2){w0_, w1_};
        }
    }
}

// ---------------- GEMM: (cnt x 6144) @ (6144 x 384), fp8 MFMA 32x32x16, BK=64, dbuf ----------------
__global__ __launch_bounds__(256) void k_gemm(const uchar* __restrict__ A,
    const uchar* __restrict__ BT, const float* __restrict__ bias,
    float* __restrict__ out, int p0)
{
    __shared__ __align__(16) uchar lds[2][2][128][64];
    int tid = threadIdx.x;
    int wave = tid >> 6, lane = tid & 63;
    int l31 = lane & 31, h = lane >> 5;
    int m0 = blockIdx.x * 128;
    int n0 = blockIdx.y * 128;
    int wr = (wave >> 1) * 64, wc = (wave & 1) * 64;

    int rr0 = wave * 16 + (lane >> 2);
    int sc0 = (lane & 3) * 16;
    const uchar* gaA0 = A  + (size_t)(p0 + m0 + rr0) * 6144 + sc0;
    const uchar* gaA1 = A  + (size_t)(p0 + m0 + rr0 + 64) * 6144 + sc0;
    const uchar* gaB0 = BT + (size_t)(n0 + rr0) * 6144 + sc0;
    const uchar* gaB1 = BT + (size_t)(n0 + rr0 + 64) * 6144 + sc0;

    f32x16 acc[2][2];
#pragma unroll
    for (int a = 0; a < 2; ++a)
#pragma unroll
        for (int bb = 0; bb < 2; ++bb)
#pragma unroll
            for (int e = 0; e < 16; ++e) acc[a][bb][e] = 0.f;

    auto stage = [&](int buf, int k0) {
        gld16(gaA0 + k0, &lds[buf][0][wave * 16][0]);
        gld16(gaA1 + k0, &lds[buf][0][64 + wave * 16][0]);
        gld16(gaB0 + k0, &lds[buf][1][wave * 16][0]);
        gld16(gaB1 + k0, &lds[buf][1][64 + wave * 16][0]);
    };

    stage(0, 0);
    for (int t = 0; t < 96; ++t) {
        __syncthreads();
        if (t + 1 < 96) stage((t + 1) & 1, (t + 1) * 64);
        const uchar* AsF = &lds[t & 1][0][0][0];
        const uchar* BsF = &lds[t & 1][1][0][0];
#pragma unroll
        for (int tp = 0; tp < 2; ++tp) {
            i64x2 av[2], bv[2];
#pragma unroll
            for (int a = 0; a < 2; ++a)
                av[a] = *(const i64x2*)(AsF + (wr + 32 * a + l31) * 64 + (h + 2 * tp) * 16);
#pragma unroll
            for (int bb = 0; bb < 2; ++bb)
                bv[bb] = *(const i64x2*)(BsF + (wc + 32 * bb + l31) * 64 + (h + 2 * tp) * 16);
#pragma unroll
            for (int a = 0; a < 2; ++a)
#pragma unroll
                for (int bb = 0; bb < 2; ++bb) {
                    acc[a][bb] = __builtin_amdgcn_mfma_f32_32x32x16_fp8_fp8(av[a][0], bv[bb][0], acc[a][bb], 0, 0, 0);
                    acc[a][bb] = __builtin_amdgcn_mfma_f32_32x32x16_fp8_fp8(av[a][1], bv[bb][1], acc[a][bb], 0, 0, 0);
                }
        }
    }

    // C layout (32x32): col = lane&31, row = (reg&3) + 8*(reg>>2) + 4*(lane>>5)
#pragma unroll
    for (int a = 0; a < 2; ++a)
#pragma unroll
        for (int bb = 0; bb < 2; ++bb)
#pragma unroll
            for (int reg = 0; reg < 16; ++reg) {
                int rowm = (reg & 3) + 8 * (reg >> 2) + 4 * h;
                int rr = wr + 32 * a + rowm;
                int cc = wc + 32 * bb + l31;
                out[(size_t)(p0 + m0 + rr) * 384 + n0 + cc] = acc[a][bb][reg] + bias[n0 + cc];
            }
}

extern "C" void kernel_launch(void* const* d_in, const int* in_sizes, int n_in,
                              void* d_out, int out_size, void* d_ws, size_t ws_size,
                              hipStream_t stream)
{
    const float* pos      = (const float*)d_in[0];
    const float* feat     = (const float*)d_in[1];
    const float* maskp    = (const float*)d_in[2];
    const int*   massign  = (const int*)d_in[4];
    const int*   memidx   = (const int*)d_in[5];
    const float* cmaskp   = (const float*)d_in[9];
    const float* norm_g   = (const float*)d_in[10];
    const float* norm_b   = (const float*)d_in[11];
    const float* w1W      = (const float*)d_in[12];
    const float* w1b      = (const float*)d_in[13];
    const float* lng      = (const float*)d_in[14];
    const float* lnb      = (const float*)d_in[15];
    const float* f1W      = (const float*)d_in[16];
    const float* f1b      = (const float*)d_in[17];
    const float* f2W      = (const float*)d_in[18];
    const float* f2b      = (const float*)d_in[19];
    const float* linW     = (const float*)d_in[20];
    const float* linb     = (const float*)d_in[21];

    char* ws = (char*)d_ws;
    ushort_t* featn  = (ushort_t*)(ws);                 // 38,535,168 B
    int* img         = (int*)(ws + 38535168);           //    401,408 B
    int* idxa        = (int*)(ws + 38936576);           //    100,352 B
    uchar* linT      = (uchar*)(ws + 39036928);         //  2,359,296 B (fp8)
    ushort_t* f1frag = (ushort_t*)(ws + 41396224);      //     24,576 B
    uchar* agg       = (uchar*)(ws + 41420800);         // up to 154,140,672 B (fp8)

    size_t avail = ws_size > 41420800 ? ws_size - 41420800 : 0;
    long long slabM = (long long)(avail / 6144);
    slabM &= ~127LL;
    if (slabM > TOTPTS) slabM = TOTPTS;
    if (slabM < 128) slabM = 128;

    k_ln<<<TOTPTS, 256, 0, stream>>>(feat, norm_g, norm_b, featn);
    hipMemsetAsync(img, 0, 401408, stream);
    k_scatter<<<392, 256, 0, stream>>>(pos, img);
    k_down<<<98, 256, 0, stream>>>(img, idxa);
    k_linT<<<dim3(96, 6), 256, 0, stream>>>(linW, linT);
    k_prep<<<48, 256, 0, stream>>>(f1W, f1frag);

    float* outF = (float*)d_out;
    for (int p0 = 0; p0 < TOTPTS; p0 += (int)slabM) {
        int cnt = TOTPTS - p0; if (cnt > (int)slabM) cnt = (int)slabM;
        k_point<<<cnt, 256, 0, stream>>>(pos, maskp, massign, memidx, cmaskp, featn, idxa, f1frag,
                w1W, w1b, lng, lnb, f1b, f2W, f2b, agg, outF, p0);
        k_gemm<<<dim3(cnt / 128, 3), 256, 0, stream>>>(agg, linT, linb, outF + OUT_FEAT_OFF, p0);
    }
}

// Round 10
// 309.229 us; speedup vs baseline: 1.0700x; 1.0700x over previous
//
#include <hip/hip_runtime.h>

typedef unsigned short ushort_t;
typedef unsigned char uchar;
typedef unsigned int uint32;
typedef __attribute__((ext_vector_type(8))) short short8;
typedef __attribute__((ext_vector_type(4))) float f32x4;
typedef __attribute__((ext_vector_type(16))) float f32x16;
typedef __attribute__((ext_vector_type(2))) unsigned int u32x2;
typedef __attribute__((ext_vector_type(2))) long long i64x2;

#define BATCH 8
#define NPTS 12544
#define CC 192
#define KCL 784
#define N2 3136
#define TOTPTS 25088        // BATCH*N2
#define OUT_FEAT_OFF 50176
#define OUT_MASK_OFF 9683968
#define FNEG 3.402823466e38f

__device__ __forceinline__ ushort_t f2bf(float f) {
    union { float f; uint32 u; } v; v.f = f;
    uint32 u = v.u;
    uint32 r = (u + 0x7FFFu + ((u >> 16) & 1u)) >> 16;
    return (ushort_t)r;
}
__device__ __forceinline__ float bf2f(ushort_t h) {
    union { uint32 u; float f; } v; v.u = ((uint32)h) << 16;
    return v.f;
}
__device__ __forceinline__ float gelu_exact(float x) {
    return 0.5f * x * (1.f + erff(x * 0.70710678118654752f));
}
__device__ __forceinline__ uchar f2e4m3(float f) {
    return (uchar)(__builtin_amdgcn_cvt_pk_fp8_f32(f, f, 0, false) & 0xFF);
}
__device__ __forceinline__ int swzc(int c) { return c ^ ((c >> 3) & 7); }

__device__ __forceinline__ void gld16(const void* g, void* l) {
    __builtin_amdgcn_global_load_lds((const __attribute__((address_space(1))) void*)g,
                                     (__attribute__((address_space(3))) void*)l, 16, 0, 0);
}

// JAX threefry2x32 with key = (0, 42)
__device__ __forceinline__ void threefry(uint32 x0, uint32 x1, uint32& y0, uint32& y1) {
    const uint32 k0 = 0u, k1 = 42u;
    const uint32 k2 = 0u ^ 42u ^ 0x1BD11BDAu;
#define ROT(v,r) (((v) << (r)) | ((v) >> (32 - (r))))
#define RND(r) { x0 += x1; x1 = ROT(x1, r); x1 ^= x0; }
    x0 += k0; x1 += k1;
    RND(13) RND(15) RND(26) RND(6)
    x0 += k1; x1 += k2 + 1u;
    RND(17) RND(29) RND(16) RND(24)
    x0 += k2; x1 += k0 + 2u;
    RND(13) RND(15) RND(26) RND(6)
    x0 += k0; x1 += k1 + 3u;
    RND(17) RND(29) RND(16) RND(24)
    x0 += k1; x1 += k2 + 4u;
    RND(13) RND(15) RND(26) RND(6)
    x0 += k2; x1 += k0 + 5u;
    y0 = x0; y1 = x1;
#undef RND
#undef ROT
}

// ---------------- LayerNorm of feat -> bf16 ----------------
__global__ __launch_bounds__(256) void k_ln(const float* __restrict__ x,
        const float* __restrict__ g, const float* __restrict__ b,
        ushort_t* __restrict__ y)
{
    int row = blockIdx.x * 4 + (threadIdx.x >> 6);
    int lane = threadIdx.x & 63;
    const float* xr = x + (size_t)row * CC;
    float v0 = xr[lane], v1 = xr[lane + 64], v2 = xr[lane + 128];
    float s = v0 + v1 + v2;
    for (int d = 32; d >= 1; d >>= 1) s += __shfl_xor(s, d, 64);
    float mu = s * (1.f / 192.f);
    float d0 = v0 - mu, d1 = v1 - mu, d2 = v2 - mu;
    float q = d0 * d0 + d1 * d1 + d2 * d2;
    for (int d = 32; d >= 1; d >>= 1) q += __shfl_xor(q, d, 64);
    float rstd = 1.f / sqrtf(q * (1.f / 192.f) + 1e-5f);
    ushort_t* yr = y + (size_t)row * CC;
    yr[lane]       = f2bf(d0 * rstd * g[lane]       + b[lane]);
    yr[lane + 64]  = f2bf(d1 * rstd * g[lane + 64]  + b[lane + 64]);
    yr[lane + 128] = f2bf(d2 * rstd * g[lane + 128] + b[lane + 128]);
}

// ---------------- points2img scatter + 2x downsample ----------------
__global__ void k_scatter(const float* __restrict__ pos, int* __restrict__ img)
{
    int t = blockIdx.x * 256 + threadIdx.x;
    int b = t / NPTS, n = t - b * NPTS;
    int x = (int)pos[(size_t)t * 2];
    int y = (int)pos[(size_t)t * 2 + 1];
    img[(size_t)b * NPTS + y * 112 + x] = n;
}

__global__ void k_down(const int* __restrict__ img, int* __restrict__ idxa)
{
    int q = blockIdx.x * 256 + threadIdx.x;
    int b = q / N2, p2 = q - b * N2;
    int r = p2 / 56, c = p2 - r * 56;
    idxa[q] = img[(size_t)b * NPTS + (2 * r) * 112 + 2 * c];
}

// ---------------- lin_W -> fp8 linT[384][6144], K physically permuted ----------------
// physical pos q: u=(q>>4)&3, v=(q>>3)&1, j=q&7; kappa = 64*(q>>6) + 8u + 32v + j
// c = kappa>>5, k = kappa&31; K_log = k*192 + c
__global__ __launch_bounds__(256) void k_linT(const float* __restrict__ W, uchar* __restrict__ T)
{
    __shared__ float tile[64][65];
    int q0 = blockIdx.x * 64, n0 = blockIdx.y * 64;
    for (int s = 0; s < 16; ++s) {
        int id = threadIdx.x + s * 256;
        int i = id >> 6, j = id & 63;
        int q = q0 + i;
        int w = q & 63;
        int kap = (q & ~63) + 8 * ((w >> 4) & 3) + 32 * ((w >> 3) & 1) + (w & 7);
        int c = kap >> 5, k = kap & 31;
        tile[i][j] = W[(size_t)(k * 192 + c) * 384 + n0 + j];
    }
    __syncthreads();
    for (int s = 0; s < 16; ++s) {
        int id = threadIdx.x + s * 256;
        int jj = id >> 6, ii = id & 63;
        T[(size_t)(n0 + jj) * 6144 + q0 + ii] = f2e4m3(tile[ii][jj]);
    }
}

// ---------------- precompute f1W MFMA B-fragments (bf16): frag[ks][w][lane][j] ----------------
__global__ __launch_bounds__(256) void k_prep(const float* __restrict__ f1W, ushort_t* __restrict__ frag)
{
    int t = blockIdx.x * 256 + threadIdx.x;   // 12288 total
    int j = t & 7;
    int lane = (t >> 3) & 63;
    int w = (t >> 9) & 3;
    int ks = t >> 11;
    int k = ks * 32 + (lane >> 4) * 8 + j;
    int o = w * 16 + (lane & 15);
    frag[t] = f2bf(f1W[k * 64 + o]);
}

// ---------------- per-point: sampling + weights + agg build (fp8, K-permuted) ----------------
__global__ __launch_bounds__(256) void k_point(
    const float* __restrict__ pos, const float* __restrict__ maskp,
    const int* __restrict__ massign, const int* __restrict__ memidx,
    const float* __restrict__ cmaskp, const ushort_t* __restrict__ featn,
    const int* __restrict__ idxarr, const ushort_t* __restrict__ f1frag,
    const float* __restrict__ w1W, const float* __restrict__ w1b,
    const float* __restrict__ lng, const float* __restrict__ lnb,
    const float* __restrict__ f1b,
    const float* __restrict__ f2W, const float* __restrict__ f2b,
    uchar* __restrict__ agg, float* __restrict__ outbuf, int p0)
{
    __shared__ float scf[128];
    __shared__ float prs[128];
    __shared__ float us[128];
    __shared__ int memv[128];
    __shared__ float fg[4][200];                      // row-major, conflict-free reads
    __shared__ __align__(16) float fgT[192][4];       // [swzc(c)][m]
    __shared__ __align__(16) ushort_t frelb[4][200];
    __shared__ float prel[4][2];
    __shared__ __align__(16) float wsm[4][32];
    __shared__ float gpart[4][4];
    __shared__ float fwv[4];

    int point = p0 + blockIdx.x;
    int b = point / N2;
    int tid = threadIdx.x;
    int wave = tid >> 6, lane = tid & 63;
    int l15 = lane & 15, l4 = lane >> 4;
    int idx_pt = idxarr[point];
    size_t browbase = (size_t)b * NPTS;

    // phase 1: scoring (128 threads)
    if (tid < 128) {
        int j = tid >> 4, i = tid & 15;
        int maj = massign[(browbase + idx_pt) * 8 + j];
        size_t roff = ((size_t)b * KCL + maj) * 16 + i;
        int mv = memidx[roff];
        float cv = cmaskp[roff];
        if (mv == idx_pt) cv = 0.f;
        float pr = fmaxf(cv, 1e-5f);
        uint32 gi = (uint32)point * 128u + (uint32)tid;
        uint32 y0, y1;
        threefry(0u, gi, y0, y1);
        uint32 bits = y0 ^ y1;
        union { uint32 u; float f; } cu; cu.u = (bits >> 9) | 0x3f800000u;
        float u = cu.f - 1.0f;
        float gum = -logf(-logf(u + 1e-20f) + 1e-20f);
        scf[tid] = logf(pr) + gum;
        prs[tid] = pr;
        us[tid] = u;
        memv[tid] = mv;
    }
    __syncthreads();   // #1

    float pdx = pos[(browbase + idx_pt) * 2];
    float pdy = pos[(browbase + idx_pt) * 2 + 1];
    if (wave == 3 && lane == 0) {
        outbuf[OUT_MASK_OFF + point] = maskp[browbase + idx_pt];
        outbuf[(size_t)point * 2]     = floorf(pdx * 0.5f);
        outbuf[(size_t)point * 2 + 1] = floorf(pdy * 0.5f);
    }

    // phase 2: per-wave redundant top-4 (barrierless)
    float a0 = scf[lane], a1 = scf[lane + 64];
    float tops[4]; int topi[4];
#pragma unroll
    for (int pass = 0; pass < 4; ++pass) {
        float s; int si;
        if (a0 >= a1) { s = a0; si = lane; } else { s = a1; si = lane + 64; }
#pragma unroll
        for (int d = 32; d >= 1; d >>= 1) {
            float s2 = __shfl_xor(s, d, 64);
            int i2 = __shfl_xor(si, d, 64);
            if (s2 > s || (s2 == s && i2 < si)) { s = s2; si = i2; }
        }
        tops[pass] = s; topi[pass] = si;
        if (si == lane) a0 = -FNEG;
        if (si == lane + 64) a1 = -FNEG;
    }
    int mc0 = memv[topi[0]], mc1 = memv[topi[1]], mc2 = memv[topi[2]];
    if (tops[2] - tops[3] < 1e-4f) {
        double b0 = log((double)prs[lane]) - log(-log((double)us[lane] + 1e-20) + 1e-20);
        double b1 = log((double)prs[lane + 64]) - log(-log((double)us[lane + 64] + 1e-20) + 1e-20);
        int mcs[3];
#pragma unroll
        for (int pass = 0; pass < 3; ++pass) {
            double s; int si;
            if (b0 >= b1) { s = b0; si = lane; } else { s = b1; si = lane + 64; }
            for (int d = 32; d >= 1; d >>= 1) {
                double s2 = __shfl_xor(s, d, 64);
                int i2 = __shfl_xor(si, d, 64);
                if (s2 > s || (s2 == s && i2 < si)) { s = s2; si = i2; }
            }
            mcs[pass] = memv[si];
            if (si == lane) b0 = -1.0e300;
            if (si == lane + 64) b1 = -1.0e300;
        }
        mc0 = mcs[0]; mc1 = mcs[1]; mc2 = mcs[2];
    }
    int myrow = idx_pt;
    if (wave == 0) myrow = mc0;
    else if (wave == 1) myrow = mc1;
    else if (wave == 2) myrow = mc2;

    // phase 3: gather (wave m -> row myrow) into fg (row-major) + fgT (swizzled c-major)
    {
        size_t rbase = (browbase + myrow) * (size_t)CC;
#pragma unroll
        for (int jj = 0; jj < 3; ++jj) {
            int c = lane + jj * 64;
            float fv = bf2f(featn[rbase + c]);
            fg[wave][c] = fv;
            fgT[swzc(c)][wave] = fv;
        }
        if (lane == 0) {
            prel[wave][0] = pos[(browbase + myrow) * 2]     - pdx;
            prel[wave][1] = pos[(browbase + myrow) * 2 + 1] - pdy;
        }
    }
    __syncthreads();   // #2

    // phase 4a: frelb build (768 elems / 256 threads) from fg (conflict-free)
#pragma unroll
    for (int it = 0; it < 3; ++it) {
        int idx = it * 256 + tid;
        int mm = idx / 192, cq = idx - mm * 192;
        frelb[mm][cq] = f2bf(fg[mm][cq] - fg[3][cq]);
    }
    // phase 4b: pos MLP (128 threads)
    if (tid < 128) {
        int mm = tid >> 5, kk = tid & 31;
        float pre = prel[mm][0] * w1W[kk] + prel[mm][1] * w1W[32 + kk] + w1b[kk];
        float s = pre;
        for (int d = 16; d >= 1; d >>= 1) s += __shfl_xor(s, d, 32);
        float mu = s * (1.f / 32.f);
        float dv = pre - mu;
        float vs = dv * dv;
        for (int d = 16; d >= 1; d >>= 1) vs += __shfl_xor(vs, d, 32);
        float var = vs * (1.f / 32.f);
        float nv = dv / sqrtf(var + 1e-5f) * lng[kk] + lnb[kk];
        wsm[mm][kk] = gelu_exact(nv);
    }
    __syncthreads();   // #3

    // phase 5: gate MFMA; wave w owns o-tile w*16
    {
        f32x4 acc = (f32x4){0.f, 0.f, 0.f, 0.f};
#pragma unroll
        for (int ks = 0; ks < 6; ++ks) {
            short8 av;
            if (l15 < 4) av = *(const short8*)(&frelb[l15][ks * 32 + l4 * 8]);
            else av = (short8){0,0,0,0,0,0,0,0};
            short8 bv = *(const short8*)(f1frag + ((size_t)(ks * 4 + wave) * 64 + lane) * 8);
            acc = __builtin_amdgcn_mfma_f32_16x16x32_bf16(av, bv, acc, 0, 0, 0);
        }
        float p0_ = 0.f, p1_ = 0.f, p2_ = 0.f, p3_ = 0.f;
        if (l4 == 0) {
            int o = wave * 16 + l15;
            float fb = f1b[o], fw2 = f2W[o];
            p0_ = gelu_exact(acc[0] + fb) * fw2;
            p1_ = gelu_exact(acc[1] + fb) * fw2;
            p2_ = gelu_exact(acc[2] + fb) * fw2;
            p3_ = gelu_exact(acc[3] + fb) * fw2;
        }
        for (int d = 8; d >= 1; d >>= 1) {
            p0_ += __shfl_xor(p0_, d, 64);
            p1_ += __shfl_xor(p1_, d, 64);
            p2_ += __shfl_xor(p2_, d, 64);
            p3_ += __shfl_xor(p3_, d, 64);
        }
        if (lane == 0) { gpart[wave][0] = p0_; gpart[wave][1] = p1_; gpart[wave][2] = p2_; gpart[wave][3] = p3_; }
    }
    __syncthreads();   // #4
    if (tid < 4) {
        float t = gpart[0][tid] + gpart[1][tid] + gpart[2][tid] + gpart[3][tid] + f2b[0];
        fwv[tid] = 1.f / (1.f + expf(-t));
    }
    __syncthreads();   // #5

    // phase 6: agg -> fp8, K-permuted layout. thread (r=tid&3, q=tid>>2): k=8r..8r+7, c=q+64*i3
    {
        int r = tid & 3, q = tid >> 2;
        float fv0 = fwv[0], fv1 = fwv[1], fv2 = fwv[2], fv3 = fwv[3];
        float wv[4][8];
#pragma unroll
        for (int m = 0; m < 4; ++m) {
            f32x4 lo = *(const f32x4*)(&wsm[m][8 * r]);
            f32x4 hi = *(const f32x4*)(&wsm[m][8 * r + 4]);
            wv[m][0] = lo[0]; wv[m][1] = lo[1]; wv[m][2] = lo[2]; wv[m][3] = lo[3];
            wv[m][4] = hi[0]; wv[m][5] = hi[1]; wv[m][6] = hi[2]; wv[m][7] = hi[3];
        }
        uchar* prow = agg + (size_t)point * 6144;
#pragma unroll
        for (int i3 = 0; i3 < 3; ++i3) {
            int c = q + 64 * i3;
            f32x4 g = *(const f32x4*)(&fgT[swzc(c)][0]);
            float g0 = g[0] * fv0, g1 = g[1] * fv1, g2 = g[2] * fv2, g3 = g[3] * fv3;
            float v[8];
#pragma unroll
            for (int i = 0; i < 8; ++i)
                v[i] = g0 * wv[0][i] + g1 * wv[1][i] + g2 * wv[2][i] + g3 * wv[3][i];
            uint32 w0_ = __builtin_amdgcn_cvt_pk_fp8_f32(v[0], v[1], 0, false);
            w0_ = __builtin_amdgcn_cvt_pk_fp8_f32(v[2], v[3], w0_, true);
            uint32 w1_ = __builtin_amdgcn_cvt_pk_fp8_f32(v[4], v[5], 0, false);
            w1_ = __builtin_amdgcn_cvt_pk_fp8_f32(v[6], v[7], w1_, true);
            // physical: 64*(c>>1) + 16*r + 8*(c&1)  (j = k&7 in byte order)
            *(u32x2*)(prow + 64 * (c >> 1) + 16 * r + 8 * (c & 1)) = (u32x2){w0_, w1_};
        }
    }
}

// ---------------- GEMM: (cnt x 6144) @ (6144 x 384), fp8 MFMA 32x32x16, BK=64, dbuf, swizzled ----------------
__global__ __launch_bounds__(256) void k_gemm(const uchar* __restrict__ A,
    const uchar* __restrict__ BT, const float* __restrict__ bias,
    float* __restrict__ out, int p0)
{
    __shared__ __align__(16) uchar lds[2][2][128][64];
    int tid = threadIdx.x;
    int wave = tid >> 6, lane = tid & 63;
    int l31 = lane & 31, h = lane >> 5;
    int m0 = blockIdx.x * 128;
    int n0 = blockIdx.y * 128;
    int wr = (wave >> 1) * 64, wc = (wave & 1) * 64;

    // staging: dest linear (lane*16); source granule pre-swizzled by (row>>1)&3 = (lane>>3)&3
    int rr0 = wave * 16 + (lane >> 2);
    int sc0 = ((lane & 3) ^ ((lane >> 3) & 3)) * 16;
    const uchar* gaA0 = A  + (size_t)(p0 + m0 + rr0) * 6144 + sc0;
    const uchar* gaA1 = A  + (size_t)(p0 + m0 + rr0 + 64) * 6144 + sc0;
    const uchar* gaB0 = BT + (size_t)(n0 + rr0) * 6144 + sc0;
    const uchar* gaB1 = BT + (size_t)(n0 + rr0 + 64) * 6144 + sc0;

    f32x16 acc[2][2];
#pragma unroll
    for (int a = 0; a < 2; ++a)
#pragma unroll
        for (int bb = 0; bb < 2; ++bb)
#pragma unroll
            for (int e = 0; e < 16; ++e) acc[a][bb][e] = 0.f;

    auto stage = [&](int buf, int k0) {
        gld16(gaA0 + k0, &lds[buf][0][wave * 16][0]);
        gld16(gaA1 + k0, &lds[buf][0][64 + wave * 16][0]);
        gld16(gaB0 + k0, &lds[buf][1][wave * 16][0]);
        gld16(gaB1 + k0, &lds[buf][1][64 + wave * 16][0]);
    };

    int fsw = (l31 >> 1) & 3;   // read-side granule XOR = (row>>1)&3, row = wr+32a+l31
    stage(0, 0);
    for (int t = 0; t < 96; ++t) {
        __syncthreads();
        if (t + 1 < 96) stage((t + 1) & 1, (t + 1) * 64);
        const uchar* AsF = &lds[t & 1][0][0][0];
        const uchar* BsF = &lds[t & 1][1][0][0];
#pragma unroll
        for (int tp = 0; tp < 2; ++tp) {
            i64x2 av[2], bv[2];
#pragma unroll
            for (int a = 0; a < 2; ++a)
                av[a] = *(const i64x2*)(AsF + (wr + 32 * a + l31) * 64 + (((h + 2 * tp)) ^ fsw) * 16);
#pragma unroll
            for (int bb = 0; bb < 2; ++bb)
                bv[bb] = *(const i64x2*)(BsF + (wc + 32 * bb + l31) * 64 + (((h + 2 * tp)) ^ fsw) * 16);
#pragma unroll
            for (int a = 0; a < 2; ++a)
#pragma unroll
                for (int bb = 0; bb < 2; ++bb) {
                    acc[a][bb] = __builtin_amdgcn_mfma_f32_32x32x16_fp8_fp8(av[a][0], bv[bb][0], acc[a][bb], 0, 0, 0);
                    acc[a][bb] = __builtin_amdgcn_mfma_f32_32x32x16_fp8_fp8(av[a][1], bv[bb][1], acc[a][bb], 0, 0, 0);
                }
        }
    }

    // C layout (32x32): col = lane&31, row = (reg&3) + 8*(reg>>2) + 4*(lane>>5)
#pragma unroll
    for (int a = 0; a < 2; ++a)
#pragma unroll
        for (int bb = 0; bb < 2; ++bb)
#pragma unroll
            for (int reg = 0; reg < 16; ++reg) {
                int rowm = (reg & 3) + 8 * (reg >> 2) + 4 * h;
                int rr = wr + 32 * a + rowm;
                int cc = wc + 32 * bb + l31;
                out[(size_t)(p0 + m0 + rr) * 384 + n0 + cc] = acc[a][bb][reg] + bias[n0 + cc];
            }
}

extern "C" void kernel_launch(void* const* d_in, const int* in_sizes, int n_in,
                              void* d_out, int out_size, void* d_ws, size_t ws_size,
                              hipStream_t stream)
{
    const float* pos      = (const float*)d_in[0];
    const float* feat     = (const float*)d_in[1];
    const float* maskp    = (const float*)d_in[2];
    const int*   massign  = (const int*)d_in[4];
    const int*   memidx   = (const int*)d_in[5];
    const float* cmaskp   = (const float*)d_in[9];
    const float* norm_g   = (const float*)d_in[10];
    const float* norm_b   = (const float*)d_in[11];
    const float* w1W      = (const float*)d_in[12];
    const float* w1b      = (const float*)d_in[13];
    const float* lng      = (const float*)d_in[14];
    const float* lnb      = (const float*)d_in[15];
    const float* f1W      = (const float*)d_in[16];
    const float* f1b      = (const float*)d_in[17];
    const float* f2W      = (const float*)d_in[18];
    const float* f2b      = (const float*)d_in[19];
    const float* linW     = (const float*)d_in[20];
    const float* linb     = (const float*)d_in[21];

    char* ws = (char*)d_ws;
    ushort_t* featn  = (ushort_t*)(ws);                 // 38,535,168 B
    int* img         = (int*)(ws + 38535168);           //    401,408 B
    int* idxa        = (int*)(ws + 38936576);           //    100,352 B
    uchar* linT      = (uchar*)(ws + 39036928);         //  2,359,296 B (fp8)
    ushort_t* f1frag = (ushort_t*)(ws + 41396224);      //     24,576 B
    uchar* agg       = (uchar*)(ws + 41420800);         // up to 154,140,672 B (fp8)

    size_t avail = ws_size > 41420800 ? ws_size - 41420800 : 0;
    long long slabM = (long long)(avail / 6144);
    slabM &= ~127LL;
    if (slabM > TOTPTS) slabM = TOTPTS;
    if (slabM < 128) slabM = 128;

    k_ln<<<TOTPTS, 256, 0, stream>>>(feat, norm_g, norm_b, featn);
    hipMemsetAsync(img, 0, 401408, stream);
    k_scatter<<<392, 256, 0, stream>>>(pos, img);
    k_down<<<98, 256, 0, stream>>>(img, idxa);
    k_linT<<<dim3(96, 6), 256, 0, stream>>>(linW, linT);
    k_prep<<<48, 256, 0, stream>>>(f1W, f1frag);

    float* outF = (float*)d_out;
    for (int p0 = 0; p0 < TOTPTS; p0 += (int)slabM) {
        int cnt = TOTPTS - p0; if (cnt > (int)slabM) cnt = (int)slabM;
        k_point<<<cnt, 256, 0, stream>>>(pos, maskp, massign, memidx, cmaskp, featn, idxa, f1frag,
                w1W, w1b, lng, lnb, f1b, f2W, f2b, agg, outF, p0);
        k_gemm<<<dim3(cnt / 128, 3), 256, 0, stream>>>(agg, linT, linb, outF + OUT_FEAT_OFF, p0);
    }
}